// Round 1
// baseline (2082.037 us; speedup 1.0000x reference)
//
#include <hip/hip_runtime.h>

#define NB 8
#define NS 1024
#define ND 768
#define NH 12
#define NHD 64
#define NLAYERS 12
#define NM (NB * NS)   // 8192 rows
#define NQKV3 (3 * ND) // 2304 output cols of fused QKV GEMM

typedef _Float16 f16;
typedef _Float16 f16x8 __attribute__((ext_vector_type(8)));
typedef _Float16 f16x4 __attribute__((ext_vector_type(4)));
typedef float f32x4 __attribute__((ext_vector_type(4)));

// ---------------------------------------------------------------------------
// One-time (per launch) weight prep:
//  Wcat[n][d] (f16, B^T layout) : n = sel*768 + h*64 + kp, contents W*[h][d][kp]
//  Wot[h][j][m] (f16)           : Wo[h][m][j] transposed for B-operand reads
// ---------------------------------------------------------------------------
__global__ __launch_bounds__(256) void prep_weights(
    const float* __restrict__ Wq, const float* __restrict__ Wk,
    const float* __restrict__ Wv, const float* __restrict__ Wo,
    f16* __restrict__ Wcat, f16* __restrict__ Wot) {
  __shared__ float tile[64][65];
  int bid = blockIdx.x, tid = threadIdx.x;
  if (bid < 432) {  // 3 sel * 12 h * 12 d-tiles
    int dt = bid % 12, hh = (bid / 12) % 12, sel = bid / 144;
    const float* W = sel == 0 ? Wq : (sel == 1 ? Wk : Wv);
    int d0 = dt * 64;
#pragma unroll
    for (int p = 0; p < 16; ++p) {
      int i = p * 4 + (tid >> 6), kp = tid & 63;
      tile[i][kp] = W[(size_t)(hh * 768 + d0 + i) * 64 + kp];
    }
    __syncthreads();
#pragma unroll
    for (int p = 0; p < 16; ++p) {
      int kp = p * 4 + (tid >> 6), i = tid & 63;
      Wcat[(size_t)(sel * 768 + hh * 64 + kp) * 768 + d0 + i] = (f16)tile[i][kp];
    }
  } else {  // 12 blocks: transpose Wo per head
    int hh = bid - 432;
#pragma unroll
    for (int p = 0; p < 16; ++p) {
      int m = p * 4 + (tid >> 6), j = tid & 63;
      tile[m][j] = Wo[(size_t)(hh * 64 + m) * 64 + j];
    }
    __syncthreads();
#pragma unroll
    for (int p = 0; p < 16; ++p) {
      int j = p * 4 + (tid >> 6), m = tid & 63;
      Wot[(size_t)(hh * 64 + j) * 64 + m] = (f16)tile[m][j];
    }
  }
}

__global__ __launch_bounds__(256) void x_to_f16(const float* __restrict__ x,
                                                f16* __restrict__ xh) {
  size_t i = (size_t)blockIdx.x * 256 + threadIdx.x;
  float4 v = reinterpret_cast<const float4*>(x)[i];
  f16x4 o;
  o[0] = (f16)v.x; o[1] = (f16)v.y; o[2] = (f16)v.z; o[3] = (f16)v.w;
  reinterpret_cast<f16x4*>(xh)[i] = o;
}

// ---------------------------------------------------------------------------
// Fused Q/K/V projection GEMM: [8192 x 768] @ [768 x 2304] (B^T layout).
// 128x128 tile, 4 waves (2x2), 16x16x32 f16 MFMA, K-step 32.
// Q is pre-scaled by 1/8 (bias folded first). V written transposed [HD][S].
// LDS rows are 64B (4 x 16B chunks); swizzle chunk ^= (row>>1)&3 -> 2-way max.
// ---------------------------------------------------------------------------
__global__ __launch_bounds__(256) void qkv_gemm(
    const f16* __restrict__ Xh, const f16* __restrict__ Wcat,
    const float* __restrict__ bq, const float* __restrict__ bk,
    const float* __restrict__ bv, f16* __restrict__ Qo, f16* __restrict__ Ko,
    f16* __restrict__ Vto) {
  __shared__ __align__(16) f16 Al[128 * 32];
  __shared__ __align__(16) f16 Bl[128 * 32];
  int tid = threadIdx.x, lane = tid & 63, wid = tid >> 6;
  int l16 = lane & 15, g4 = lane >> 4;
  int r0 = blockIdx.x * 128, n0 = blockIdx.y * 128;
  int wm = wid & 1, wn = wid >> 1;
  f32x4 acc[4][4] = {};

  for (int kk = 0; kk < 768; kk += 32) {
#pragma unroll
    for (int ss = 0; ss < 2; ++ss) {
      int slot = ss * 256 + tid;
      int row = slot >> 2, ch = slot & 3;
      int chs = ch ^ ((row >> 1) & 3);
      f16x8 va = *(const f16x8*)(Xh + (size_t)(r0 + row) * 768 + kk + ch * 8);
      *(f16x8*)(Al + row * 32 + chs * 8) = va;
      f16x8 vb = *(const f16x8*)(Wcat + (size_t)(n0 + row) * 768 + kk + ch * 8);
      *(f16x8*)(Bl + row * 32 + chs * 8) = vb;
    }
    __syncthreads();
    f16x8 af[4], bf[4];
#pragma unroll
    for (int mf = 0; mf < 4; ++mf) {
      int row = wm * 64 + mf * 16 + l16;
      int ch = g4 ^ ((row >> 1) & 3);
      af[mf] = *(const f16x8*)(Al + row * 32 + ch * 8);
    }
#pragma unroll
    for (int nf = 0; nf < 4; ++nf) {
      int row = wn * 64 + nf * 16 + l16;
      int ch = g4 ^ ((row >> 1) & 3);
      bf[nf] = *(const f16x8*)(Bl + row * 32 + ch * 8);
    }
#pragma unroll
    for (int mf = 0; mf < 4; ++mf)
#pragma unroll
      for (int nf = 0; nf < 4; ++nf)
        acc[mf][nf] = __builtin_amdgcn_mfma_f32_16x16x32_f16(af[mf], bf[nf],
                                                             acc[mf][nf], 0, 0, 0);
    __syncthreads();
  }
  // epilogue: bias, (Q only) 1/8 scale, route to Q / K / V^T
#pragma unroll
  for (int nf = 0; nf < 4; ++nf) {
    int gcol = n0 + wn * 64 + nf * 16 + l16;
    int sel = gcol / 768, rem = gcol % 768;
    int hh = rem >> 6, kp = rem & 63;
    const float* bp = sel == 0 ? bq : (sel == 1 ? bk : bv);
    float bia = bp[hh * 64 + kp];
    float scl = sel == 0 ? 0.125f : 1.f;
#pragma unroll
    for (int mf = 0; mf < 4; ++mf) {
#pragma unroll
      for (int r = 0; r < 4; ++r) {
        int grow = r0 + wm * 64 + mf * 16 + g4 * 4 + r;
        int b = grow >> 10, s = grow & 1023;
        f16 hv = (f16)((acc[mf][nf][r] + bia) * scl);
        if (sel == 0)
          Qo[((size_t)(b * 12 + hh) * 1024 + s) * 64 + kp] = hv;
        else if (sel == 1)
          Ko[((size_t)(b * 12 + hh) * 1024 + s) * 64 + kp] = hv;
        else
          Vto[((size_t)(b * 12 + hh) * 64 + kp) * 1024 + s] = hv;
      }
    }
  }
}

// ---------------------------------------------------------------------------
// Flash attention + fused Wo projection. Block = (b, h, 64 q-rows), 4 waves,
// each wave owns 16 q-rows. K/V tiles of 64 in LDS (128B rows, swizzle
// byte ^= (row&7)<<4). Online softmax in fp32; P goes D-layout -> A-layout
// through a padded per-wave LDS scratch (stride 68 floats -> 2-way max).
// ---------------------------------------------------------------------------
__global__ __launch_bounds__(256) void attn_fused(
    const f16* __restrict__ Qg, const f16* __restrict__ Kg,
    const f16* __restrict__ Vt, const f16* __restrict__ Wot,
    const float* __restrict__ bo, f16* __restrict__ XhOut,
    float* __restrict__ Fout, int last) {
  __shared__ __align__(16) f16 Kl[64 * 64];
  __shared__ __align__(16) f16 Vl[64 * 64];
  __shared__ __align__(16) float Pl[4][16 * 68];
  int tid = threadIdx.x, lane = tid & 63, wid = tid >> 6;
  int l16 = lane & 15, g4 = lane >> 4;
  int q0 = blockIdx.x * 64;
  int hh = blockIdx.y, bb = blockIdx.z;
  size_t bh = (size_t)bb * 12 + hh;
  const f16* Qp = Qg + bh * (1024 * 64);
  const f16* Kp = Kg + bh * (1024 * 64);
  const f16* Vp = Vt + bh * (64 * 1024);

  f16x8 qa[2];
#pragma unroll
  for (int kf = 0; kf < 2; ++kf)
    qa[kf] = *(const f16x8*)(Qp + (size_t)(q0 + wid * 16 + l16) * 64 + kf * 32 + g4 * 8);

  float mrun[4], lrun[4];
  f32x4 oacc[4] = {};
#pragma unroll
  for (int r = 0; r < 4; ++r) { mrun[r] = -1e30f; lrun[r] = 0.f; }

  for (int t0 = 0; t0 < 1024; t0 += 64) {
#pragma unroll
    for (int ss = 0; ss < 2; ++ss) {
      int slot = ss * 256 + tid;
      int row = slot >> 3, ch = slot & 7;
      int chs = ch ^ (row & 7);
      f16x8 kv = *(const f16x8*)(Kp + (size_t)(t0 + row) * 64 + ch * 8);
      *(f16x8*)(Kl + row * 64 + chs * 8) = kv;
      f16x8 vv = *(const f16x8*)(Vp + (size_t)row * 1024 + t0 + ch * 8);
      *(f16x8*)(Vl + row * 64 + chs * 8) = vv;
    }
    __syncthreads();
    // scores S[16q x 64t] (Q already scaled by 1/8)
    f32x4 sc[4] = {};
#pragma unroll
    for (int nf = 0; nf < 4; ++nf) {
#pragma unroll
      for (int kf = 0; kf < 2; ++kf) {
        int row = nf * 16 + l16;
        int ch = (kf * 4 + g4) ^ (row & 7);
        f16x8 kb = *(const f16x8*)(Kl + row * 64 + ch * 8);
        sc[nf] = __builtin_amdgcn_mfma_f32_16x16x32_f16(qa[kf], kb, sc[nf], 0, 0, 0);
      }
    }
    // online softmax (fp32); write P to per-wave LDS scratch
#pragma unroll
    for (int r = 0; r < 4; ++r) {
      float mx = fmaxf(fmaxf(sc[0][r], sc[1][r]), fmaxf(sc[2][r], sc[3][r]));
      mx = fmaxf(mx, __shfl_xor(mx, 1));
      mx = fmaxf(mx, __shfl_xor(mx, 2));
      mx = fmaxf(mx, __shfl_xor(mx, 4));
      mx = fmaxf(mx, __shfl_xor(mx, 8));
      float mnew = fmaxf(mrun[r], mx);
      float corr = __expf(mrun[r] - mnew);
      float rs = 0.f;
#pragma unroll
      for (int nf = 0; nf < 4; ++nf) {
        float p = __expf(sc[nf][r] - mnew);
        Pl[wid][(g4 * 4 + r) * 68 + nf * 16 + l16] = p;
        rs += p;
      }
      rs += __shfl_xor(rs, 1);
      rs += __shfl_xor(rs, 2);
      rs += __shfl_xor(rs, 4);
      rs += __shfl_xor(rs, 8);
      lrun[r] = lrun[r] * corr + rs;
      mrun[r] = mnew;
#pragma unroll
      for (int mf = 0; mf < 4; ++mf) oacc[mf][r] *= corr;
    }
    __syncthreads();
    // PV: A-frags from P scratch, B-frags from V^T tile
    f16x8 pa[2];
#pragma unroll
    for (int kf = 0; kf < 2; ++kf) {
      const float* src = &Pl[wid][l16 * 68 + kf * 32 + g4 * 8];
      f32x4 v0 = *(const f32x4*)src;
      f32x4 v1 = *(const f32x4*)(src + 4);
      f16x8 t;
      t[0] = (f16)v0[0]; t[1] = (f16)v0[1]; t[2] = (f16)v0[2]; t[3] = (f16)v0[3];
      t[4] = (f16)v1[0]; t[5] = (f16)v1[1]; t[6] = (f16)v1[2]; t[7] = (f16)v1[3];
      pa[kf] = t;
    }
#pragma unroll
    for (int mf = 0; mf < 4; ++mf) {
#pragma unroll
      for (int kf = 0; kf < 2; ++kf) {
        int row = mf * 16 + l16;
        int ch = (kf * 4 + g4) ^ (row & 7);
        f16x8 vb = *(const f16x8*)(Vl + row * 64 + ch * 8);
        oacc[mf] = __builtin_amdgcn_mfma_f32_16x16x32_f16(pa[kf], vb, oacc[mf], 0, 0, 0);
      }
    }
    __syncthreads();
  }
  // ctx = oacc / l  -> LDS scratch -> A-frags for Wo projection
#pragma unroll
  for (int r = 0; r < 4; ++r) {
    float inv = 1.f / lrun[r];
#pragma unroll
    for (int mf = 0; mf < 4; ++mf)
      Pl[wid][(g4 * 4 + r) * 68 + mf * 16 + l16] = oacc[mf][r] * inv;
  }
  __syncthreads();
  f16x8 ca[2];
#pragma unroll
  for (int kf = 0; kf < 2; ++kf) {
    const float* src = &Pl[wid][l16 * 68 + kf * 32 + g4 * 8];
    f32x4 v0 = *(const f32x4*)src;
    f32x4 v1 = *(const f32x4*)(src + 4);
    f16x8 t;
    t[0] = (f16)v0[0]; t[1] = (f16)v0[1]; t[2] = (f16)v0[2]; t[3] = (f16)v0[3];
    t[4] = (f16)v1[0]; t[5] = (f16)v1[1]; t[6] = (f16)v1[2]; t[7] = (f16)v1[3];
    ca[kf] = t;
  }
  const f16* Wop = Wot + hh * (64 * 64);
  f32x4 acc2[4] = {};
#pragma unroll
  for (int nf = 0; nf < 4; ++nf)
#pragma unroll
    for (int kf = 0; kf < 2; ++kf) {
      f16x8 wb = *(const f16x8*)(Wop + (nf * 16 + l16) * 64 + kf * 32 + g4 * 8);
      acc2[nf] = __builtin_amdgcn_mfma_f32_16x16x32_f16(ca[kf], wb, acc2[nf], 0, 0, 0);
    }
#pragma unroll
  for (int nf = 0; nf < 4; ++nf) {
    int j = nf * 16 + l16;
    float bia = bo[hh * 64 + j];
#pragma unroll
    for (int r = 0; r < 4; ++r) {
      int s = q0 + wid * 16 + g4 * 4 + r;
      float val = acc2[nf][r] + bia;
      size_t oidx = ((size_t)bb * 1024 + s) * 768 + hh * 64 + j;
      if (last)
        Fout[oidx] = val;
      else
        XhOut[oidx] = (f16)val;
    }
  }
}

// ---------------------------------------------------------------------------
extern "C" void kernel_launch(void* const* d_in, const int* in_sizes, int n_in,
                              void* d_out, int out_size, void* d_ws,
                              size_t ws_size, hipStream_t stream) {
  const float* x = (const float*)d_in[0];
  const float* Wq = (const float*)d_in[1];
  const float* bq = (const float*)d_in[2];
  const float* Wk = (const float*)d_in[3];
  const float* bk = (const float*)d_in[4];
  const float* Wv = (const float*)d_in[5];
  const float* bv = (const float*)d_in[6];
  const float* Wo = (const float*)d_in[7];
  const float* bo = (const float*)d_in[8];
  float* out = (float*)d_out;

  char* ws = (char*)d_ws;
  size_t off = 0;
  auto alloc = [&](size_t bytes) -> void* {
    void* p = ws + off;
    off += (bytes + 255) & ~(size_t)255;
    return p;
  };
  f16* Wcat = (f16*)alloc((size_t)NQKV3 * ND * 2);   // 3.54 MB
  f16* Wot = (f16*)alloc((size_t)NH * 64 * 64 * 2);  // 98 KB
  f16* Xh = (f16*)alloc((size_t)NM * ND * 2);        // 12.6 MB
  f16* Qb = (f16*)alloc((size_t)NM * ND * 2);        // 12.6 MB (B*H*S*HD)
  f16* Kb = (f16*)alloc((size_t)NM * ND * 2);
  f16* Vtb = (f16*)alloc((size_t)NM * ND * 2);

  prep_weights<<<444, 256, 0, stream>>>(Wq, Wk, Wv, Wo, Wcat, Wot);
  x_to_f16<<<(NM * ND / 4) / 256, 256, 0, stream>>>(x, Xh);
  for (int l = 0; l < NLAYERS; ++l) {
    qkv_gemm<<<dim3(NM / 128, NQKV3 / 128), 256, 0, stream>>>(
        Xh, Wcat, bq, bk, bv, Qb, Kb, Vtb);
    attn_fused<<<dim3(NS / 64, NH, NB), 256, 0, stream>>>(
        Qb, Kb, Vtb, Wot, bo, Xh, out, l == NLAYERS - 1);
  }
}

// Round 2
// 1643.155 us; speedup vs baseline: 1.2671x; 1.2671x over previous
//
#include <hip/hip_runtime.h>

#define NB 8
#define NS 1024
#define ND 768
#define NH 12
#define NHD 64
#define NLAYERS 12
#define NM (NB * NS)   // 8192 rows
#define NQKV3 (3 * ND) // 2304 output cols of fused QKV GEMM
#define QSCALE 0.1803368802f  // (1/8) * log2(e): softmax runs in exp2 domain

typedef _Float16 f16;
typedef _Float16 f16x8 __attribute__((ext_vector_type(8)));
typedef _Float16 f16x4 __attribute__((ext_vector_type(4)));
typedef float f32x4 __attribute__((ext_vector_type(4)));

__device__ inline float fexp2(float x) {
  float r;
  asm("v_exp_f32 %0, %1" : "=v"(r) : "v"(x));
  return r;
}

// ---------------------------------------------------------------------------
// One-time weight prep.
//  Wcat[n][d] (f16, B^T layout), n = sel*768 + h*64 + kp:
//    sel 0: Wq[h][d][kp]   sel 1: Wk[h][d][kp]   sel 2: (Wv@Wo)[h][d][kp]
//  bvo[h*64+j] = sum_m bv[h][m]*Wo[h][m][j] + bo[h][j]
//  (softmax rows sum to 1, so ctx@Wo + bo == P@(V@Wo) + bvo — Wo is folded.)
// ---------------------------------------------------------------------------
__global__ __launch_bounds__(256) void prep_weights(
    const float* __restrict__ Wq, const float* __restrict__ Wk,
    const float* __restrict__ Wv, const float* __restrict__ Wo,
    const float* __restrict__ bv, const float* __restrict__ bo,
    f16* __restrict__ Wcat, float* __restrict__ bvo) {
  __shared__ float t0[64][65];
  __shared__ float t1[64 * 64];
  int bid = blockIdx.x, tid = threadIdx.x;
  if (bid < 288) {  // Q,K transposes
    int dt = bid % 12, hh = (bid / 12) % 12, sel = bid / 144;
    const float* W = sel == 0 ? Wq : Wk;
    int d0 = dt * 64;
#pragma unroll
    for (int p = 0; p < 16; ++p) {
      int i = p * 4 + (tid >> 6), kp = tid & 63;
      t0[i][kp] = W[(size_t)(hh * 768 + d0 + i) * 64 + kp];
    }
    __syncthreads();
#pragma unroll
    for (int p = 0; p < 16; ++p) {
      int kp = p * 4 + (tid >> 6), i = tid & 63;
      Wcat[(size_t)(sel * 768 + hh * 64 + kp) * 768 + d0 + i] = (f16)t0[i][kp];
    }
  } else if (bid < 432) {  // V@Wo per (head, d-tile), f32 compute
    int idx = bid - 288, hh = idx / 12, dt = idx % 12, d0 = dt * 64;
#pragma unroll
    for (int p = 0; p < 16; ++p) {
      int i = p * 4 + (tid >> 6), m = tid & 63;
      t0[i][m] = Wv[(size_t)(hh * 768 + d0 + i) * 64 + m];
      t1[i * 64 + m] = Wo[(size_t)(hh * 64 + i) * 64 + m];
    }
    __syncthreads();
    int j = tid & 63;
    for (int p = 0; p < 16; ++p) {
      int i = p * 4 + (tid >> 6);
      float a = 0.f;
      for (int m = 0; m < 64; ++m) a += t0[i][m] * t1[m * 64 + j];
      Wcat[(size_t)(1536 + hh * 64 + j) * 768 + d0 + i] = (f16)a;
    }
  } else {  // bvo
    for (int base = 0; base < 768; base += 256) {
      int idx = base + tid, h2 = idx >> 6, j = idx & 63;
      float a = bo[idx];
      for (int m = 0; m < 64; ++m)
        a += bv[h2 * 64 + m] * Wo[(size_t)(h2 * 64 + m) * 64 + j];
      bvo[idx] = a;
    }
  }
}

__global__ __launch_bounds__(256) void x_to_f16(const float* __restrict__ x,
                                                f16* __restrict__ xh) {
  size_t i = (size_t)blockIdx.x * 256 + threadIdx.x;
  float4 v = reinterpret_cast<const float4*>(x)[i];
  f16x4 o;
  o[0] = (f16)v.x; o[1] = (f16)v.y; o[2] = (f16)v.z; o[3] = (f16)v.w;
  reinterpret_cast<f16x4*>(xh)[i] = o;
}

// ---------------------------------------------------------------------------
// Fused Q/K/Vtilde projection: [8192 x 768] @ [768 x 2304] (B^T layout).
// 128x128 tile, 4 waves, 16x16x32 f16 MFMA, BK=32.
// Double-buffered LDS, ONE barrier per K-step, loads issued before MFMA.
// Q pre-scaled by log2e/8. Vtilde (=X@Wv@Wo) written transposed [HD][S].
// ---------------------------------------------------------------------------
__global__ __launch_bounds__(256) void qkv_gemm(
    const f16* __restrict__ Xh, const f16* __restrict__ Wcat,
    const float* __restrict__ bq, const float* __restrict__ bk,
    f16* __restrict__ Qo, f16* __restrict__ Ko, f16* __restrict__ Vto) {
  __shared__ __align__(16) f16 Al[2][128 * 32];
  __shared__ __align__(16) f16 Bl[2][128 * 32];
  int tid = threadIdx.x, lane = tid & 63, wid = tid >> 6;
  int l16 = lane & 15, g4 = lane >> 4;
  int r0 = blockIdx.x * 128, n0 = blockIdx.y * 128;
  int wm = wid & 1, wn = wid >> 1;
  int srow = tid >> 2, sch = tid & 3;  // staging slot; ss adds 64 rows
  f32x4 acc[4][4] = {};
  f16x8 ra[2], rb[2];

  auto load_ab = [&](int kk) {
#pragma unroll
    for (int ss = 0; ss < 2; ++ss) {
      int row = ss * 64 + srow;
      ra[ss] = *(const f16x8*)(Xh + (size_t)(r0 + row) * 768 + kk + sch * 8);
      rb[ss] = *(const f16x8*)(Wcat + (size_t)(n0 + row) * 768 + kk + sch * 8);
    }
  };
  auto store_ab = [&](int buf) {
#pragma unroll
    for (int ss = 0; ss < 2; ++ss) {
      int row = ss * 64 + srow;
      int chs = sch ^ ((row >> 1) & 3);
      *(f16x8*)(Al[buf] + row * 32 + chs * 8) = ra[ss];
      *(f16x8*)(Bl[buf] + row * 32 + chs * 8) = rb[ss];
    }
  };

  load_ab(0);
  store_ab(0);
  __syncthreads();
  int cur = 0;
  for (int kk = 0; kk < 768; kk += 32) {
    bool more = kk + 32 < 768;
    if (more) load_ab(kk + 32);  // global->reg, overlaps MFMAs below
    f16x8 af[4], bf[4];
#pragma unroll
    for (int mf = 0; mf < 4; ++mf) {
      int row = wm * 64 + mf * 16 + l16;
      int ch = g4 ^ ((row >> 1) & 3);
      af[mf] = *(const f16x8*)(Al[cur] + row * 32 + ch * 8);
    }
#pragma unroll
    for (int nf = 0; nf < 4; ++nf) {
      int row = wn * 64 + nf * 16 + l16;
      int ch = g4 ^ ((row >> 1) & 3);
      bf[nf] = *(const f16x8*)(Bl[cur] + row * 32 + ch * 8);
    }
#pragma unroll
    for (int mf = 0; mf < 4; ++mf)
#pragma unroll
      for (int nf = 0; nf < 4; ++nf)
        acc[mf][nf] = __builtin_amdgcn_mfma_f32_16x16x32_f16(af[mf], bf[nf],
                                                             acc[mf][nf], 0, 0, 0);
    if (more) {
      store_ab(cur ^ 1);  // vmcnt wait lands here, not at a dead barrier
      __syncthreads();
      cur ^= 1;
    }
  }
  // epilogue: bias, (Q only) log2e/8 scale, route to Q / K / Vtilde^T
#pragma unroll
  for (int nf = 0; nf < 4; ++nf) {
    int gcol = n0 + wn * 64 + nf * 16 + l16;
    int sel = gcol / 768, rem = gcol % 768;
    int hh = rem >> 6, kp = rem & 63;
    float bia = sel == 0 ? bq[hh * 64 + kp] : (sel == 1 ? bk[hh * 64 + kp] : 0.f);
    float scl = sel == 0 ? QSCALE : 1.f;
#pragma unroll
    for (int mf = 0; mf < 4; ++mf) {
#pragma unroll
      for (int r = 0; r < 4; ++r) {
        int grow = r0 + wm * 64 + mf * 16 + g4 * 4 + r;
        int b = grow >> 10, s = grow & 1023;
        f16 hv = (f16)((acc[mf][nf][r] + bia) * scl);
        if (sel == 0)
          Qo[((size_t)(b * 12 + hh) * 1024 + s) * 64 + kp] = hv;
        else if (sel == 1)
          Ko[((size_t)(b * 12 + hh) * 1024 + s) * 64 + kp] = hv;
        else
          Vto[((size_t)(b * 12 + hh) * 64 + kp) * 1024 + s] = hv;
      }
    }
  }
}

// ---------------------------------------------------------------------------
// Flash attention, Wo already folded into Vtilde. Block = (b, h, 128 q-rows),
// 4 waves x 32 q-rows (2 m-frags). KV tiles of 64, DOUBLE-BUFFERED in LDS:
// one barrier per tile, next tile's global loads issued before compute.
// Softmax in exp2 domain (Q pre-scaled by log2e/8). P round-trips through a
// per-wave f32 LDS scratch (stride 68), reused across the two m-frags.
// ---------------------------------------------------------------------------
__global__ __launch_bounds__(256, 3) void attn_fused(
    const f16* __restrict__ Qg, const f16* __restrict__ Kg,
    const f16* __restrict__ Vt, const float* __restrict__ bvo,
    f16* __restrict__ XhOut, float* __restrict__ Fout, int last) {
  __shared__ __align__(16) f16 Kl[2][64 * 64];
  __shared__ __align__(16) f16 Vl[2][64 * 64];
  __shared__ __align__(16) float Pl[4][16 * 68];
  int tid = threadIdx.x, lane = tid & 63, wid = tid >> 6;
  int l16 = lane & 15, g4 = lane >> 4;
  int q0 = blockIdx.x * 128;
  int hh = blockIdx.y, bb = blockIdx.z;
  size_t bh = (size_t)bb * 12 + hh;
  const f16* Qp = Qg + bh * (1024 * 64);
  const f16* Kp = Kg + bh * (1024 * 64);
  const f16* Vp = Vt + bh * (64 * 1024);

  f16x8 qa[2][2];
#pragma unroll
  for (int mq = 0; mq < 2; ++mq)
#pragma unroll
    for (int kf = 0; kf < 2; ++kf)
      qa[mq][kf] = *(const f16x8*)(Qp + (size_t)(q0 + wid * 32 + mq * 16 + l16) * 64 +
                                   kf * 32 + g4 * 8);

  int srow = tid >> 3, sch = tid & 7;  // staging slot; ss adds 32 rows
  f16x8 rk[2], rv[2];
  auto kv_load = [&](int t0) {
#pragma unroll
    for (int ss = 0; ss < 2; ++ss) {
      int row = ss * 32 + srow;
      rk[ss] = *(const f16x8*)(Kp + (size_t)(t0 + row) * 64 + sch * 8);
      rv[ss] = *(const f16x8*)(Vp + (size_t)row * 1024 + t0 + sch * 8);
    }
  };
  auto kv_store = [&](int buf) {
#pragma unroll
    for (int ss = 0; ss < 2; ++ss) {
      int row = ss * 32 + srow;
      int chs = sch ^ (row & 7);
      *(f16x8*)(Kl[buf] + row * 64 + chs * 8) = rk[ss];
      *(f16x8*)(Vl[buf] + row * 64 + chs * 8) = rv[ss];
    }
  };

  float mrun[2][4], lrun[2][4];
  f32x4 oacc[2][4] = {};
#pragma unroll
  for (int mq = 0; mq < 2; ++mq)
#pragma unroll
    for (int r = 0; r < 4; ++r) { mrun[mq][r] = -1e30f; lrun[mq][r] = 0.f; }

  kv_load(0);
  kv_store(0);
  __syncthreads();
  int cur = 0;
  for (int t = 0; t < 16; ++t) {
    bool more = t < 15;
    if (more) kv_load((t + 1) * 64);  // in flight across the whole tile
    const f16* Kc = Kl[cur];
    const f16* Vc = Vl[cur];
    // scores S[32q x 64t] in exp2 domain
    f32x4 sc[2][4] = {};
#pragma unroll
    for (int nf = 0; nf < 4; ++nf) {
#pragma unroll
      for (int kf = 0; kf < 2; ++kf) {
        int row = nf * 16 + l16;
        int ch = (kf * 4 + g4) ^ (row & 7);
        f16x8 kb = *(const f16x8*)(Kc + row * 64 + ch * 8);
#pragma unroll
        for (int mq = 0; mq < 2; ++mq)
          sc[mq][nf] = __builtin_amdgcn_mfma_f32_16x16x32_f16(qa[mq][kf], kb,
                                                              sc[mq][nf], 0, 0, 0);
      }
    }
#pragma unroll
    for (int mq = 0; mq < 2; ++mq) {
      // online softmax for this m-frag's 16 rows
#pragma unroll
      for (int r = 0; r < 4; ++r) {
        float mx = fmaxf(fmaxf(sc[mq][0][r], sc[mq][1][r]),
                         fmaxf(sc[mq][2][r], sc[mq][3][r]));
        mx = fmaxf(mx, __shfl_xor(mx, 1));
        mx = fmaxf(mx, __shfl_xor(mx, 2));
        mx = fmaxf(mx, __shfl_xor(mx, 4));
        mx = fmaxf(mx, __shfl_xor(mx, 8));
        float mold = mrun[mq][r];
        float mnew = fmaxf(mold, mx);
        float corr = fexp2(mold - mnew);
        float rs = 0.f;
#pragma unroll
        for (int nf = 0; nf < 4; ++nf) {
          float p = fexp2(sc[mq][nf][r] - mnew);
          Pl[wid][(g4 * 4 + r) * 68 + nf * 16 + l16] = p;
          rs += p;
        }
        rs += __shfl_xor(rs, 1);
        rs += __shfl_xor(rs, 2);
        rs += __shfl_xor(rs, 4);
        rs += __shfl_xor(rs, 8);
        lrun[mq][r] = lrun[mq][r] * corr + rs;
        mrun[mq][r] = mnew;
#pragma unroll
        for (int nd = 0; nd < 4; ++nd) oacc[mq][nd][r] *= corr;
      }
      // P: D-layout -> A-frags via per-wave scratch (same-wave RAW: no barrier)
      f16x8 pa[2];
#pragma unroll
      for (int kf = 0; kf < 2; ++kf) {
        const float* src = &Pl[wid][l16 * 68 + kf * 32 + g4 * 8];
        f32x4 v0 = *(const f32x4*)src;
        f32x4 v1 = *(const f32x4*)(src + 4);
        f16x8 tt;
        tt[0] = (f16)v0[0]; tt[1] = (f16)v0[1]; tt[2] = (f16)v0[2]; tt[3] = (f16)v0[3];
        tt[4] = (f16)v1[0]; tt[5] = (f16)v1[1]; tt[6] = (f16)v1[2]; tt[7] = (f16)v1[3];
        pa[kf] = tt;
      }
#pragma unroll
      for (int nd = 0; nd < 4; ++nd) {
#pragma unroll
        for (int kf = 0; kf < 2; ++kf) {
          int row = nd * 16 + l16;
          int ch = (kf * 4 + g4) ^ (row & 7);
          f16x8 vb = *(const f16x8*)(Vc + row * 64 + ch * 8);
          oacc[mq][nd] = __builtin_amdgcn_mfma_f32_16x16x32_f16(pa[kf], vb,
                                                                oacc[mq][nd], 0, 0, 0);
        }
      }
    }
    if (more) {
      kv_store(cur ^ 1);  // disjoint buffer; prior readers passed last barrier
      __syncthreads();
      cur ^= 1;
    }
  }
  // epilogue: normalize, add folded bias (bv@Wo + bo), write
#pragma unroll
  for (int mq = 0; mq < 2; ++mq)
#pragma unroll
    for (int nd = 0; nd < 4; ++nd) {
      int j = nd * 16 + l16;
      float bia = bvo[hh * 64 + j];
#pragma unroll
      for (int r = 0; r < 4; ++r) {
        int s = q0 + wid * 32 + mq * 16 + g4 * 4 + r;
        float val = oacc[mq][nd][r] / lrun[mq][r] + bia;
        size_t oidx = ((size_t)bb * 1024 + s) * 768 + hh * 64 + j;
        if (last)
          Fout[oidx] = val;
        else
          XhOut[oidx] = (f16)val;
      }
    }
}

// ---------------------------------------------------------------------------
extern "C" void kernel_launch(void* const* d_in, const int* in_sizes, int n_in,
                              void* d_out, int out_size, void* d_ws,
                              size_t ws_size, hipStream_t stream) {
  const float* x = (const float*)d_in[0];
  const float* Wq = (const float*)d_in[1];
  const float* bq = (const float*)d_in[2];
  const float* Wk = (const float*)d_in[3];
  const float* bk = (const float*)d_in[4];
  const float* Wv = (const float*)d_in[5];
  const float* bv = (const float*)d_in[6];
  const float* Wo = (const float*)d_in[7];
  const float* bo = (const float*)d_in[8];
  float* out = (float*)d_out;

  char* ws = (char*)d_ws;
  size_t off = 0;
  auto alloc = [&](size_t bytes) -> void* {
    void* p = ws + off;
    off += (bytes + 255) & ~(size_t)255;
    return p;
  };
  f16* Wcat = (f16*)alloc((size_t)NQKV3 * ND * 2);  // 3.54 MB
  float* bvo = (float*)alloc(768 * 4);
  f16* Xh = (f16*)alloc((size_t)NM * ND * 2);   // 12.6 MB
  f16* Qb = (f16*)alloc((size_t)NM * ND * 2);   // B*H*S*HD
  f16* Kb = (f16*)alloc((size_t)NM * ND * 2);
  f16* Vtb = (f16*)alloc((size_t)NM * ND * 2);

  prep_weights<<<433, 256, 0, stream>>>(Wq, Wk, Wv, Wo, bv, bo, Wcat, bvo);
  x_to_f16<<<(NM * ND / 4) / 256, 256, 0, stream>>>(x, Xh);
  for (int l = 0; l < NLAYERS; ++l) {
    qkv_gemm<<<dim3(NM / 128, NQKV3 / 128), 256, 0, stream>>>(
        Xh, Wcat, bq, bk, Qb, Kb, Vtb);
    attn_fused<<<dim3(NS / 128, NH, NB), 256, 0, stream>>>(
        Qb, Kb, Vtb, bvo, Xh, out, l == NLAYERS - 1);
  }
}

// Round 3
// 1147.822 us; speedup vs baseline: 1.8139x; 1.4315x over previous
//
#include <hip/hip_runtime.h>

#define NB 8
#define NS 1024
#define ND 768
#define NH 12
#define NHD 64
#define NLAYERS 12
#define NM (NB * NS)   // 8192 rows
#define NQKV3 (3 * ND) // 2304 output cols of fused QKV GEMM
#define QSCALE 0.1803368802f  // (1/8) * log2(e): softmax runs in exp2 domain

typedef _Float16 f16;
typedef _Float16 f16x8 __attribute__((ext_vector_type(8)));
typedef _Float16 f16x4 __attribute__((ext_vector_type(4)));
typedef _Float16 f16x2 __attribute__((ext_vector_type(2)));
typedef float f32x4 __attribute__((ext_vector_type(4)));
typedef float f32x16 __attribute__((ext_vector_type(16)));
typedef unsigned int u32x4 __attribute__((ext_vector_type(4)));

__device__ inline float fexp2(float x) {
  float r;
  asm("v_exp_f32 %0, %1" : "=v"(r) : "v"(x));
  return r;
}

// ---------------------------------------------------------------------------
// One-time weight prep.
//  Wcat[n][d] (f16, B^T layout), n = sel*768 + h*64 + kp:
//    sel 0: Wq[h][d][kp]   sel 1: Wk[h][d][kp]   sel 2: (Wv@Wo)[h][d][kp]
//  bvo[h*64+j] = sum_m bv[h][m]*Wo[h][m][j] + bo[h][j]
//  (softmax rows sum to 1, so ctx@Wo + bo == P@(V@Wo) + bvo — Wo is folded.)
// ---------------------------------------------------------------------------
__global__ __launch_bounds__(256) void prep_weights(
    const float* __restrict__ Wq, const float* __restrict__ Wk,
    const float* __restrict__ Wv, const float* __restrict__ Wo,
    const float* __restrict__ bv, const float* __restrict__ bo,
    f16* __restrict__ Wcat, float* __restrict__ bvo) {
  __shared__ float t0[64][65];
  __shared__ float t1[64 * 64];
  int bid = blockIdx.x, tid = threadIdx.x;
  if (bid < 288) {  // Q,K transposes
    int dt = bid % 12, hh = (bid / 12) % 12, sel = bid / 144;
    const float* W = sel == 0 ? Wq : Wk;
    int d0 = dt * 64;
#pragma unroll
    for (int p = 0; p < 16; ++p) {
      int i = p * 4 + (tid >> 6), kp = tid & 63;
      t0[i][kp] = W[(size_t)(hh * 768 + d0 + i) * 64 + kp];
    }
    __syncthreads();
#pragma unroll
    for (int p = 0; p < 16; ++p) {
      int kp = p * 4 + (tid >> 6), i = tid & 63;
      Wcat[(size_t)(sel * 768 + hh * 64 + kp) * 768 + d0 + i] = (f16)t0[i][kp];
    }
  } else if (bid < 432) {  // V@Wo per (head, d-tile), f32 compute
    int idx = bid - 288, hh = idx / 12, dt = idx % 12, d0 = dt * 64;
#pragma unroll
    for (int p = 0; p < 16; ++p) {
      int i = p * 4 + (tid >> 6), m = tid & 63;
      t0[i][m] = Wv[(size_t)(hh * 768 + d0 + i) * 64 + m];
      t1[i * 64 + m] = Wo[(size_t)(hh * 64 + i) * 64 + m];
    }
    __syncthreads();
    int j = tid & 63;
    for (int p = 0; p < 16; ++p) {
      int i = p * 4 + (tid >> 6);
      float a = 0.f;
      for (int m = 0; m < 64; ++m) a += t0[i][m] * t1[m * 64 + j];
      Wcat[(size_t)(1536 + hh * 64 + j) * 768 + d0 + i] = (f16)a;
    }
  } else {  // bvo
    for (int base = 0; base < 768; base += 256) {
      int idx = base + tid, h2 = idx >> 6, j = idx & 63;
      float a = bo[idx];
      for (int m = 0; m < 64; ++m)
        a += bv[h2 * 64 + m] * Wo[(size_t)(h2 * 64 + m) * 64 + j];
      bvo[idx] = a;
    }
  }
}

__global__ __launch_bounds__(256) void x_to_f16(const float* __restrict__ x,
                                                f16* __restrict__ xh) {
  size_t i = (size_t)blockIdx.x * 256 + threadIdx.x;
  float4 v = reinterpret_cast<const float4*>(x)[i];
  f16x4 o;
  o[0] = (f16)v.x; o[1] = (f16)v.y; o[2] = (f16)v.z; o[3] = (f16)v.w;
  reinterpret_cast<f16x4*>(xh)[i] = o;
}

// ---------------------------------------------------------------------------
// Fused Q/K/Vtilde projection: [8192 x 768] @ [768 x 2304] (B^T layout).
// 128x128 tile, 4 waves, 16x16x32 f16 MFMA, BK=32, double-buffered LDS,
// one barrier per K-step. Q pre-scaled by log2e/8. Vtilde written ^T [HD][S].
// ---------------------------------------------------------------------------
__global__ __launch_bounds__(256) void qkv_gemm(
    const f16* __restrict__ Xh, const f16* __restrict__ Wcat,
    const float* __restrict__ bq, const float* __restrict__ bk,
    f16* __restrict__ Qo, f16* __restrict__ Ko, f16* __restrict__ Vto) {
  __shared__ __align__(16) f16 Al[2][128 * 32];
  __shared__ __align__(16) f16 Bl[2][128 * 32];
  int tid = threadIdx.x, lane = tid & 63, wid = tid >> 6;
  int l16 = lane & 15, g4 = lane >> 4;
  int r0 = blockIdx.x * 128, n0 = blockIdx.y * 128;
  int wm = wid & 1, wn = wid >> 1;
  int srow = tid >> 2, sch = tid & 3;
  f32x4 acc[4][4] = {};
  f16x8 ra[2], rb[2];

  auto load_ab = [&](int kk) {
#pragma unroll
    for (int ss = 0; ss < 2; ++ss) {
      int row = ss * 64 + srow;
      ra[ss] = *(const f16x8*)(Xh + (size_t)(r0 + row) * 768 + kk + sch * 8);
      rb[ss] = *(const f16x8*)(Wcat + (size_t)(n0 + row) * 768 + kk + sch * 8);
    }
  };
  auto store_ab = [&](int buf) {
#pragma unroll
    for (int ss = 0; ss < 2; ++ss) {
      int row = ss * 64 + srow;
      int chs = sch ^ ((row >> 1) & 3);
      *(f16x8*)(Al[buf] + row * 32 + chs * 8) = ra[ss];
      *(f16x8*)(Bl[buf] + row * 32 + chs * 8) = rb[ss];
    }
  };

  load_ab(0);
  store_ab(0);
  __syncthreads();
  int cur = 0;
  for (int kk = 0; kk < 768; kk += 32) {
    bool more = kk + 32 < 768;
    if (more) load_ab(kk + 32);
    f16x8 af[4], bf[4];
#pragma unroll
    for (int mf = 0; mf < 4; ++mf) {
      int row = wm * 64 + mf * 16 + l16;
      int ch = g4 ^ ((row >> 1) & 3);
      af[mf] = *(const f16x8*)(Al[cur] + row * 32 + ch * 8);
    }
#pragma unroll
    for (int nf = 0; nf < 4; ++nf) {
      int row = wn * 64 + nf * 16 + l16;
      int ch = g4 ^ ((row >> 1) & 3);
      bf[nf] = *(const f16x8*)(Bl[cur] + row * 32 + ch * 8);
    }
#pragma unroll
    for (int mf = 0; mf < 4; ++mf)
#pragma unroll
      for (int nf = 0; nf < 4; ++nf)
        acc[mf][nf] = __builtin_amdgcn_mfma_f32_16x16x32_f16(af[mf], bf[nf],
                                                             acc[mf][nf], 0, 0, 0);
    if (more) {
      store_ab(cur ^ 1);
      __syncthreads();
      cur ^= 1;
    }
  }
#pragma unroll
  for (int nf = 0; nf < 4; ++nf) {
    int gcol = n0 + wn * 64 + nf * 16 + l16;
    int sel = gcol / 768, rem = gcol % 768;
    int hh = rem >> 6, kp = rem & 63;
    float bia = sel == 0 ? bq[hh * 64 + kp] : (sel == 1 ? bk[hh * 64 + kp] : 0.f);
    float scl = sel == 0 ? QSCALE : 1.f;
#pragma unroll
    for (int mf = 0; mf < 4; ++mf) {
#pragma unroll
      for (int r = 0; r < 4; ++r) {
        int grow = r0 + wm * 64 + mf * 16 + g4 * 4 + r;
        int b = grow >> 10, s = grow & 1023;
        f16 hv = (f16)((acc[mf][nf][r] + bia) * scl);
        if (sel == 0)
          Qo[((size_t)(b * 12 + hh) * 1024 + s) * 64 + kp] = hv;
        else if (sel == 1)
          Ko[((size_t)(b * 12 + hh) * 1024 + s) * 64 + kp] = hv;
        else
          Vto[((size_t)(b * 12 + hh) * 64 + kp) * 1024 + s] = hv;
      }
    }
  }
}

// ---------------------------------------------------------------------------
// Flash attention, swapped-operand 32x32x16 MFMA, in-register softmax (T12),
// defer-max (T13), Wo folded into Vtilde. Block = (b, h, 128 q-rows), 4 waves
// x 32 q-rows. D-frag of mfma(K,Q): col = q = lane&31 -> each lane owns one
// softmax row (32 of 64 t's; partner lane^32 has the rest). KV tiles 64,
// double-buffered swizzled LDS, 1 barrier/tile. P stays in registers:
// cvt_pkrtz pairs + one xor-32 exchange per kf build the PV B-frags.
// ---------------------------------------------------------------------------
struct SMemKV { f16 K[2][64 * 64]; f16 V[2][64 * 64]; };
union SMemU { SMemKV kv; float O[4 * 32 * 68]; };

__global__ __launch_bounds__(256, 3) void attn_fused(
    const f16* __restrict__ Qg, const f16* __restrict__ Kg,
    const f16* __restrict__ Vt, const float* __restrict__ bvo,
    f16* __restrict__ XhOut, float* __restrict__ Fout, int last) {
  __shared__ __align__(16) SMemU sm;
  int tid = threadIdx.x, lane = tid & 63, wid = tid >> 6;
  int l32 = lane & 31, hi = lane >> 5;
  int q0 = blockIdx.x * 128;
  int hh = blockIdx.y, bb = blockIdx.z;
  size_t bh = (size_t)bb * 12 + hh;
  const f16* Qp = Qg + bh * (1024 * 64);
  const f16* Kp = Kg + bh * (1024 * 64);
  const f16* Vp = Vt + bh * (64 * 1024);

  // Q as B-operand frags: lane -> q-row = q0+wid*32+l32, k = kf*16 + hi*8 + j
  f16x8 qf[4];
#pragma unroll
  for (int kf = 0; kf < 4; ++kf)
    qf[kf] = *(const f16x8*)(Qp + (size_t)(q0 + wid * 32 + l32) * 64 + kf * 16 + hi * 8);

  // staging: 256 threads x 2 chunks each for K and V tiles (64 rows x 8 chunks)
  f16x8 rk[2], rv[2];
  auto kv_load = [&](int t0) {
#pragma unroll
    for (int ss = 0; ss < 2; ++ss) {
      int cl = ss * 256 + tid, r = cl >> 3, c = cl & 7;
      rk[ss] = *(const f16x8*)(Kp + (size_t)(t0 + r) * 64 + c * 8);
      rv[ss] = *(const f16x8*)(Vp + (size_t)r * 1024 + t0 + c * 8);
    }
  };
  auto kv_store = [&](int buf) {
#pragma unroll
    for (int ss = 0; ss < 2; ++ss) {
      int cl = ss * 256 + tid, r = cl >> 3, c = cl & 7;
      int cs = c ^ (r & 7);
      *(f16x8*)(sm.kv.K[buf] + r * 64 + cs * 8) = rk[ss];
      *(f16x8*)(sm.kv.V[buf] + r * 64 + cs * 8) = rv[ss];
    }
  };

  f32x16 oacc0 = {}, oacc1 = {};
  float m = -1e30f, lsum = 0.f;

  kv_load(0);
  kv_store(0);
  __syncthreads();
  int cur = 0;
  for (int t = 0; t < 16; ++t) {
    bool more = t < 15;
    if (more) kv_load((t + 1) * 64);
    const f16* Kc = sm.kv.K[cur];
    const f16* Vc = sm.kv.V[cur];
    // S^T[t][q]: sc0 = t 0..31 tile, sc1 = t 32..63 tile (rows per D-layout)
    f32x16 sc0 = {}, sc1 = {};
#pragma unroll
    for (int kf = 0; kf < 4; ++kf) {
      int ch = (2 * kf + hi) ^ (l32 & 7);
      f16x8 k0 = *(const f16x8*)(Kc + l32 * 64 + ch * 8);
      sc0 = __builtin_amdgcn_mfma_f32_32x32x16_f16(k0, qf[kf], sc0, 0, 0, 0);
      f16x8 k1 = *(const f16x8*)(Kc + (32 + l32) * 64 + ch * 8);
      sc1 = __builtin_amdgcn_mfma_f32_32x32x16_f16(k1, qf[kf], sc1, 0, 0, 0);
    }
    // lane-local row max over 32 values + partner exchange
    float mx[16];
#pragma unroll
    for (int j = 0; j < 16; ++j) mx[j] = fmaxf(sc0[j], sc1[j]);
#pragma unroll
    for (int s = 8; s >= 1; s >>= 1)
#pragma unroll
      for (int j = 0; j < 8; ++j)
        if (j < s) mx[j] = fmaxf(mx[j], mx[j + s]);
    float pmax = fmaxf(mx[0], __shfl_xor(mx[0], 32));
    // defer-max (T13): rescale only when a row grew past THR=8 (exp2 domain)
    if (__any(pmax > m + 8.f)) {
      float mn = fmaxf(m, pmax);
      float c = fexp2(m - mn);
      lsum *= c;
#pragma unroll
      for (int j = 0; j < 16; ++j) { oacc0[j] *= c; oacc1[j] *= c; }
      m = mn;
    }
    // p = exp2(s - m), per-quad: partial sums + packed f16 words
    unsigned w[8][2];
    float qs[8];
#pragma unroll
    for (int qd = 0; qd < 8; ++qd) {
      float a0, a1, a2, a3;
      if (qd < 4) {
        a0 = fexp2(sc0[qd * 4 + 0] - m); a1 = fexp2(sc0[qd * 4 + 1] - m);
        a2 = fexp2(sc0[qd * 4 + 2] - m); a3 = fexp2(sc0[qd * 4 + 3] - m);
      } else {
        a0 = fexp2(sc1[(qd - 4) * 4 + 0] - m); a1 = fexp2(sc1[(qd - 4) * 4 + 1] - m);
        a2 = fexp2(sc1[(qd - 4) * 4 + 2] - m); a3 = fexp2(sc1[(qd - 4) * 4 + 3] - m);
      }
      qs[qd] = (a0 + a1) + (a2 + a3);
      w[qd][0] = __builtin_bit_cast(unsigned, __builtin_amdgcn_cvt_pkrtz(a0, a1));
      w[qd][1] = __builtin_bit_cast(unsigned, __builtin_amdgcn_cvt_pkrtz(a2, a3));
    }
    lsum += ((qs[0] + qs[1]) + (qs[2] + qs[3])) + ((qs[4] + qs[5]) + (qs[6] + qs[7]));
    // PV: per kf build P^T B-frag (own quad + partner quad via xor-32), 2 MFMAs
#pragma unroll
    for (int kf = 0; kf < 4; ++kf) {
      int QB = (kf >> 1) * 4 + 2 * (kf & 1);
      unsigned lo0, lo1, hi0, hi1;
      {
        unsigned s0 = hi ? w[QB][0] : w[QB + 1][0];
        unsigned s1 = hi ? w[QB][1] : w[QB + 1][1];
        unsigned r0 = __shfl_xor(s0, 32);
        unsigned r1 = __shfl_xor(s1, 32);
        lo0 = hi ? r0 : w[QB][0];
        lo1 = hi ? r1 : w[QB][1];
        hi0 = hi ? w[QB + 1][0] : r0;
        hi1 = hi ? w[QB + 1][1] : r1;
      }
      u32x4 pw = {lo0, lo1, hi0, hi1};
      f16x8 pf = __builtin_bit_cast(f16x8, pw);
      int ch = (2 * kf + hi) ^ (l32 & 7);
      f16x8 v0 = *(const f16x8*)(Vc + l32 * 64 + ch * 8);
      oacc0 = __builtin_amdgcn_mfma_f32_32x32x16_f16(v0, pf, oacc0, 0, 0, 0);
      f16x8 v1 = *(const f16x8*)(Vc + (32 + l32) * 64 + ch * 8);
      oacc1 = __builtin_amdgcn_mfma_f32_32x32x16_f16(v1, pf, oacc1, 0, 0, 0);
    }
    if (more) {
      kv_store(cur ^ 1);
      __syncthreads();
      cur ^= 1;
    }
  }
  // epilogue: normalize, transpose via LDS (reuses KV space), coalesced write
  float lt = lsum + __shfl_xor(lsum, 32);
  float inv = 1.f / lt;
  __syncthreads();
  float* Ow = sm.O + wid * (32 * 68) + l32 * 68;
#pragma unroll
  for (int dt = 0; dt < 2; ++dt) {
#pragma unroll
    for (int g = 0; g < 4; ++g) {
      int d0 = dt * 32 + g * 8 + hi * 4;
      f32x4 st;
      if (dt == 0) {
        st[0] = oacc0[g * 4 + 0] * inv; st[1] = oacc0[g * 4 + 1] * inv;
        st[2] = oacc0[g * 4 + 2] * inv; st[3] = oacc0[g * 4 + 3] * inv;
      } else {
        st[0] = oacc1[g * 4 + 0] * inv; st[1] = oacc1[g * 4 + 1] * inv;
        st[2] = oacc1[g * 4 + 2] * inv; st[3] = oacc1[g * 4 + 3] * inv;
      }
      *(f32x4*)(Ow + d0) = st;
    }
  }
  __syncthreads();
  int base_q = bb * 1024 + q0;
#pragma unroll
  for (int p = 0; p < 8; ++p) {
    int cl = p * 256 + tid;
    int row = cl >> 4, c = cl & 15;
    f32x4 v = *(const f32x4*)(sm.O + (row >> 5) * (32 * 68) + (row & 31) * 68 + c * 4);
    float4 bv4 = *(const float4*)(bvo + hh * 64 + c * 4);
    v[0] += bv4.x; v[1] += bv4.y; v[2] += bv4.z; v[3] += bv4.w;
    size_t off = (size_t)(base_q + row) * 768 + hh * 64 + c * 4;
    if (last) {
      *(f32x4*)(Fout + off) = v;
    } else {
      f16x4 hq;
      hq[0] = (f16)v[0]; hq[1] = (f16)v[1]; hq[2] = (f16)v[2]; hq[3] = (f16)v[3];
      *(f16x4*)(XhOut + off) = hq;
    }
  }
}

// ---------------------------------------------------------------------------
extern "C" void kernel_launch(void* const* d_in, const int* in_sizes, int n_in,
                              void* d_out, int out_size, void* d_ws,
                              size_t ws_size, hipStream_t stream) {
  const float* x = (const float*)d_in[0];
  const float* Wq = (const float*)d_in[1];
  const float* bq = (const float*)d_in[2];
  const float* Wk = (const float*)d_in[3];
  const float* bk = (const float*)d_in[4];
  const float* Wv = (const float*)d_in[5];
  const float* bv = (const float*)d_in[6];
  const float* Wo = (const float*)d_in[7];
  const float* bo = (const float*)d_in[8];
  float* out = (float*)d_out;

  char* ws = (char*)d_ws;
  size_t off = 0;
  auto alloc = [&](size_t bytes) -> void* {
    void* p = ws + off;
    off += (bytes + 255) & ~(size_t)255;
    return p;
  };
  f16* Wcat = (f16*)alloc((size_t)NQKV3 * ND * 2);  // 3.54 MB
  float* bvo = (float*)alloc(768 * 4);
  f16* Xh = (f16*)alloc((size_t)NM * ND * 2);   // 12.6 MB
  f16* Qb = (f16*)alloc((size_t)NM * ND * 2);   // B*H*S*HD
  f16* Kb = (f16*)alloc((size_t)NM * ND * 2);
  f16* Vtb = (f16*)alloc((size_t)NM * ND * 2);

  prep_weights<<<433, 256, 0, stream>>>(Wq, Wk, Wv, Wo, bv, bo, Wcat, bvo);
  x_to_f16<<<(NM * ND / 4) / 256, 256, 0, stream>>>(x, Xh);
  for (int l = 0; l < NLAYERS; ++l) {
    qkv_gemm<<<dim3(NM / 128, NQKV3 / 128), 256, 0, stream>>>(
        Xh, Wcat, bq, bk, Qb, Kb, Vtb);
    attn_fused<<<dim3(NS / 128, NH, NB), 256, 0, stream>>>(
        Qb, Kb, Vtb, bvo, Xh, out, l == NLAYERS - 1);
  }
}